// Round 12
// baseline (217.557 us; speedup 1.0000x reference)
//
#include <hip/hip_runtime.h>
#include <math.h>

#define N_NODES 100000
#define N_EDGES 1600000
#define EPS_    1e-5f
#define PAD     64          // ELL row capacity; P(Poisson(16) > 64) ~ 1e-20
#define SCOL    48          // staged ELL columns; P(deg > 48) ~ 1e-12/node

// R21: gather MLP rework. R20: fused=73us (edge-scatter floor, lin hidden),
// gather ~68us latency-bound (FETCH 98MB would be 16us at BW peak; 17 serial
// 128B row-reads/node, 8 in flight, grid only ~6 blocks/CU). New gather:
// half-wave channel-pair split -- each lane loads a packed uint (2 channels),
// lanes 0-31 read neighbor j, lanes 32-63 read neighbor j+1 -> one load inst
// fetches TWO rows; 8-load batch = 16 rows in flight; VMEM inst/node 17->9.
// Cross-half shfl_xor + one redistribution shuffle restore lane=channel for
// the unchanged LN epilogue. 128-thr/32-node blocks (grid 3125) for fill.
// fused_edge_lin and scale byte-identical to R20.

#define NCHUNK_E 782        // ceil(E/2048)
#define EPB_E    2048
#define NB_EDGE  (NCHUNK_E * 8)      // 6256 blocks; sibling p owns one dst range
#define PART_SZ  12500      // N_NODES / 8

#define LIN_WAVES 1563      // ceil(N/64): one wave = 64 nodes, lane = node

#define GF_NODES 32         // nodes per gather block
#define NB_GATHER ((N_NODES + GF_NODES - 1) / GF_NODES)   // 3125

typedef float v16f __attribute__((ext_vector_type(16)));

// ---- bf16 helpers (raw ushort storage, RNE on pack) -----------------------
__device__ __forceinline__ float bf2f(unsigned short u) {
    union { unsigned int i; float f; } v; v.i = (unsigned int)u << 16; return v.f;
}
__device__ __forceinline__ unsigned short f2bf(float f) {
    union { float f; unsigned int i; } v; v.f = f;
    unsigned int b = v.i + 0x7FFFu + ((v.i >> 16) & 1u);   // round-to-nearest-even
    return (unsigned short)(b >> 16);
}
__device__ __forceinline__ unsigned int pk2(float lo, float hi) {
    return (unsigned int)f2bf(lo) | ((unsigned int)f2bf(hi) << 16);
}
// packed-uint (2 x bf16) -> two floats
__device__ __forceinline__ float u2lo(unsigned int v) {
    union { unsigned int i; float f; } u; u.i = v << 16; return u.f;
}
__device__ __forceinline__ float u2hi(unsigned int v) {
    union { unsigned int i; float f; } u; u.i = v & 0xFFFF0000u; return u.f;
}

#define FMA16(A, wv0, wv1, wv2, wv3)                                          \
    do {                                                                      \
        A[0]  = fmaf(hk, wv0.x, A[0]);  A[1]  = fmaf(hk, wv0.y, A[1]);        \
        A[2]  = fmaf(hk, wv0.z, A[2]);  A[3]  = fmaf(hk, wv0.w, A[3]);        \
        A[4]  = fmaf(hk, wv1.x, A[4]);  A[5]  = fmaf(hk, wv1.y, A[5]);        \
        A[6]  = fmaf(hk, wv1.z, A[6]);  A[7]  = fmaf(hk, wv1.w, A[7]);        \
        A[8]  = fmaf(hk, wv2.x, A[8]);  A[9]  = fmaf(hk, wv2.y, A[9]);        \
        A[10] = fmaf(hk, wv2.z, A[10]); A[11] = fmaf(hk, wv2.w, A[11]);       \
        A[12] = fmaf(hk, wv3.x, A[12]); A[13] = fmaf(hk, wv3.y, A[13]);       \
        A[14] = fmaf(hk, wv3.z, A[14]); A[15] = fmaf(hk, wv3.w, A[15]);       \
    } while (0)

// ---------------------------------------------------------------------------
// Kernel 1: fused edge scatter + lin (R19/R20 form, unchanged).
// ---------------------------------------------------------------------------
__global__ void fused_edge_lin_kernel(const int* __restrict__ src,
                                      const int* __restrict__ dst,
                                      const float* __restrict__ x,
                                      const float* __restrict__ W1,
                                      const float* __restrict__ b1,
                                      const float* __restrict__ Wg,
                                      int* __restrict__ cnt,
                                      int* __restrict__ ell,
                                      unsigned short* __restrict__ hb_g)
{
    const int tl    = threadIdx.x;
    const int part  = blockIdx.x & 7;          // aligns with round-robin XCD dispatch
    const int chunk = blockIdx.x >> 3;
    const int lo    = part * PART_SZ;
    const int hi    = lo + PART_SZ;

    // ---- Phase A issue: load 8 edges, claim owned ones -------------------
    const int ebase = chunk * EPB_E + tl * 8;
    int dv[8], sv[8], pos[8];
    if (ebase + 8 <= N_EDGES) {
        const int4 d0 = *(const int4*)(dst + ebase);
        const int4 d1 = *(const int4*)(dst + ebase + 4);
        const int4 s0 = *(const int4*)(src + ebase);
        const int4 s1 = *(const int4*)(src + ebase + 4);
        dv[0] = d0.x; dv[1] = d0.y; dv[2] = d0.z; dv[3] = d0.w;
        dv[4] = d1.x; dv[5] = d1.y; dv[6] = d1.z; dv[7] = d1.w;
        sv[0] = s0.x; sv[1] = s0.y; sv[2] = s0.z; sv[3] = s0.w;
        sv[4] = s1.x; sv[5] = s1.y; sv[6] = s1.z; sv[7] = s1.w;
    } else {
#pragma unroll
        for (int j = 0; j < 8; ++j) {
            const int e = ebase + j;
            if (e < N_EDGES) { dv[j] = dst[e]; sv[j] = src[e]; }
            else             { dv[j] = -1;     sv[j] = 0;      }
        }
    }
#pragma unroll
    for (int j = 0; j < 8; ++j) {
        pos[j] = -1;
        if (dv[j] >= lo && dv[j] < hi) pos[j] = atomicAdd(&cnt[dv[j]], 1);
    }

    // ---- Phase B: lin (waves 0..1562), atomic returns drain underneath ---
    const int wave = blockIdx.x * 4 + (tl >> 6);
    if (wave < LIN_WAVES) {
        const int lane = tl & 63;
        const int n    = wave * 64 + lane;
        const bool act = (n < N_NODES);
        float x0 = 0.f, x1 = 0.f, x2 = 0.f;
        if (act) { x0 = x[n * 3]; x1 = x[n * 3 + 1]; x2 = x[n * 3 + 2]; }

        v16f a0, a1, a2, a3;
#pragma unroll
        for (int i = 0; i < 16; ++i) { a0[i] = 0.f; a1[i] = 0.f; a2[i] = 0.f; a3[i] = 0.f; }

        for (int k = 0; k < 64; ++k) {
            const float w0 = W1[k];               // wave-uniform
            const float w1 = W1[64 + k];
            const float w2 = W1[128 + k];
            const float bb = b1[k];
            const float hk = fmaxf(fmaf(x0, w0, fmaf(x1, w1, fmaf(x2, w2, bb))), 0.f);

            const float4* __restrict__ r4 = (const float4*)(Wg + (size_t)k * 64);
            {
                const float4 p0 = r4[0], p1 = r4[1], p2 = r4[2], p3 = r4[3];
                FMA16(a0, p0, p1, p2, p3);
            }
            {
                const float4 p0 = r4[4], p1 = r4[5], p2 = r4[6], p3 = r4[7];
                FMA16(a1, p0, p1, p2, p3);
            }
            {
                const float4 p0 = r4[8], p1 = r4[9], p2 = r4[10], p3 = r4[11];
                FMA16(a2, p0, p1, p2, p3);
            }
            {
                const float4 p0 = r4[12], p1 = r4[13], p2 = r4[14], p3 = r4[15];
                FMA16(a3, p0, p1, p2, p3);
            }
        }

        if (act) {
            uint4* __restrict__ dp = (uint4*)(hb_g + (size_t)n * 64);
            dp[0] = make_uint4(pk2(a0[0],  a0[1]),  pk2(a0[2],  a0[3]),
                               pk2(a0[4],  a0[5]),  pk2(a0[6],  a0[7]));
            dp[1] = make_uint4(pk2(a0[8],  a0[9]),  pk2(a0[10], a0[11]),
                               pk2(a0[12], a0[13]), pk2(a0[14], a0[15]));
            dp[2] = make_uint4(pk2(a1[0],  a1[1]),  pk2(a1[2],  a1[3]),
                               pk2(a1[4],  a1[5]),  pk2(a1[6],  a1[7]));
            dp[3] = make_uint4(pk2(a1[8],  a1[9]),  pk2(a1[10], a1[11]),
                               pk2(a1[12], a1[13]), pk2(a1[14], a1[15]));
            dp[4] = make_uint4(pk2(a2[0],  a2[1]),  pk2(a2[2],  a2[3]),
                               pk2(a2[4],  a2[5]),  pk2(a2[6],  a2[7]));
            dp[5] = make_uint4(pk2(a2[8],  a2[9]),  pk2(a2[10], a2[11]),
                               pk2(a2[12], a2[13]), pk2(a2[14], a2[15]));
            dp[6] = make_uint4(pk2(a3[0],  a3[1]),  pk2(a3[2],  a3[3]),
                               pk2(a3[4],  a3[5]),  pk2(a3[6],  a3[7]));
            dp[7] = make_uint4(pk2(a3[8],  a3[9]),  pk2(a3[10], a3[11]),
                               pk2(a3[12], a3[13]), pk2(a3[14], a3[15]));
        }
    }

    // ---- Phase A complete: scattered ELL stores --------------------------
#pragma unroll
    for (int j = 0; j < 8; ++j)
        if (pos[j] >= 0 && pos[j] < PAD) ell[dv[j] * PAD + pos[j]] = sv[j];
}

// ---------------------------------------------------------------------------
// Kernel 2: hb_g[n][c] *= rsqrt(cnt[n]+1)  (in place, dword grain, ~6-10 us)
// ---------------------------------------------------------------------------
__global__ void scale_kernel(const int* __restrict__ cnt,
                             unsigned int* __restrict__ g2)
{
    const int t = blockIdx.x * blockDim.x + threadIdx.x;
    if (t >= N_NODES * 32) return;
    const int node = t >> 5;
    const float di = rsqrtf((float)(cnt[node] + 1));
    const unsigned int v = g2[t];
    const float lo = bf2f((unsigned short)(v & 0xFFFFu)) * di;
    const float hi = bf2f((unsigned short)(v >> 16)) * di;
    g2[t] = (unsigned int)f2bf(lo) | ((unsigned int)f2bf(hi) << 16);
}

// ---------------------------------------------------------------------------
// Kernel 3: gather + epilogue, half-wave channel-pair split.
// 128 threads = 2 waves, 32 nodes per block. Each lane covers channels
// (2*l32, 2*l32+1) via packed uint loads; half 0 handles self + odd
// neighbors, half 1 even neighbors -> one load inst fetches two rows.
// Cross-half shfl_xor + redistribution shuffle restore lane=channel.
// ---------------------------------------------------------------------------
__global__ void gather_final_kernel(const unsigned short* __restrict__ hb_g,
                                    const int* __restrict__ cnt,
                                    const int* __restrict__ ell,
                                    const float* __restrict__ x,
                                    const float* __restrict__ W1,
                                    const float* __restrict__ b1,
                                    const float* __restrict__ bg,
                                    const float* __restrict__ gamma,
                                    const float* __restrict__ beta,
                                    float* __restrict__ out)
{
    __shared__ int sell[GF_NODES * SCOL];   // 6 KB
    __shared__ int lcnt[GF_NODES];
    const int tl = threadIdx.x;             // 128 threads = 2 waves
    const int b  = blockIdx.x;
    const int nb = b * GF_NODES;

    if (tl < GF_NODES) {
        const int n = nb + tl;
        lcnt[tl] = (n < N_NODES) ? cnt[n] : 0;
    }
    {
        const int r = tl >> 2;              // row 0..31
        const int q = tl & 3;               // quad 0..3
        const int nr = nb + r;
        if (nr < N_NODES) {
            const int4* __restrict__ grow = (const int4*)(ell + (size_t)nr * PAD);
            int4* __restrict__ srow = (int4*)(sell + r * SCOL);
            srow[q]     = grow[q];          // cols  0..15
            srow[q + 4] = grow[q + 4];      // cols 16..31
            srow[q + 8] = grow[q + 8];      // cols 32..47
        }
    }
    __syncthreads();

    const int lane = tl & 63;
    const int w    = tl >> 6;               // wave 0..1
    const int half = lane >> 5;             // 0: self+odd neighbors, 1: even
    const int l32  = lane & 31;
    const int off  = 1 - half;

    const float w0 = W1[lane], w1 = W1[64 + lane], w2 = W1[128 + lane];
    const float bb1 = b1[lane];
    const float bgl = bg[lane];
    const float g0 = gamma[lane], g1 = gamma[64 + lane];
    const float be0 = beta[lane], be1 = beta[64 + lane];

    for (int nl = w; nl < GF_NODES; nl += 2) {
        const int n = nb + nl;
        if (n >= N_NODES) break;            // only the last block's tail

        const int c    = lcnt[nl];
        const float di = rsqrtf((float)(c + 1));
        const int deg  = (c < PAD) ? c : PAD;
        const int dstg = (deg < SCOL) ? deg : SCOL;
        const int* row = sell + nl * SCOL;

        const float xx0 = x[n * 3], xx1 = x[n * 3 + 1], xx2 = x[n * 3 + 2];

        float acc0 = 0.f, acc1 = 0.f;
        if (half == 0) {                    // self (prescaled), half 0 only
            const unsigned int v = *(const unsigned int*)(hb_g + (size_t)n * 64 + l32 * 2);
            acc0 += u2lo(v); acc1 += u2hi(v);
        }

        int bj = 0;
        for (; bj + 16 <= dstg; bj += 16) { // 8 loads in flight = 16 rows
            const int i0 = row[bj + 0  + off];
            const int i1 = row[bj + 2  + off];
            const int i2 = row[bj + 4  + off];
            const int i3 = row[bj + 6  + off];
            const int i4 = row[bj + 8  + off];
            const int i5 = row[bj + 10 + off];
            const int i6 = row[bj + 12 + off];
            const int i7 = row[bj + 14 + off];
            const unsigned int v0 = *(const unsigned int*)(hb_g + (size_t)i0 * 64 + l32 * 2);
            const unsigned int v1 = *(const unsigned int*)(hb_g + (size_t)i1 * 64 + l32 * 2);
            const unsigned int v2 = *(const unsigned int*)(hb_g + (size_t)i2 * 64 + l32 * 2);
            const unsigned int v3 = *(const unsigned int*)(hb_g + (size_t)i3 * 64 + l32 * 2);
            const unsigned int v4 = *(const unsigned int*)(hb_g + (size_t)i4 * 64 + l32 * 2);
            const unsigned int v5 = *(const unsigned int*)(hb_g + (size_t)i5 * 64 + l32 * 2);
            const unsigned int v6 = *(const unsigned int*)(hb_g + (size_t)i6 * 64 + l32 * 2);
            const unsigned int v7 = *(const unsigned int*)(hb_g + (size_t)i7 * 64 + l32 * 2);
            acc0 += ((u2lo(v0) + u2lo(v1)) + (u2lo(v2) + u2lo(v3)))
                  + ((u2lo(v4) + u2lo(v5)) + (u2lo(v6) + u2lo(v7)));
            acc1 += ((u2hi(v0) + u2hi(v1)) + (u2hi(v2) + u2hi(v3)))
                  + ((u2hi(v4) + u2hi(v5)) + (u2hi(v6) + u2hi(v7)));
        }
        if (bj + 8 <= dstg) {               // 4 loads = 8 rows
            const int i0 = row[bj + 0 + off];
            const int i1 = row[bj + 2 + off];
            const int i2 = row[bj + 4 + off];
            const int i3 = row[bj + 6 + off];
            const unsigned int v0 = *(const unsigned int*)(hb_g + (size_t)i0 * 64 + l32 * 2);
            const unsigned int v1 = *(const unsigned int*)(hb_g + (size_t)i1 * 64 + l32 * 2);
            const unsigned int v2 = *(const unsigned int*)(hb_g + (size_t)i2 * 64 + l32 * 2);
            const unsigned int v3 = *(const unsigned int*)(hb_g + (size_t)i3 * 64 + l32 * 2);
            acc0 += (u2lo(v0) + u2lo(v1)) + (u2lo(v2) + u2lo(v3));
            acc1 += (u2hi(v0) + u2hi(v1)) + (u2hi(v2) + u2hi(v3));
            bj += 8;
        }
        for (; bj < deg; bj += 2) {         // pair tail (+ rare global overflow)
            const int my = bj + off;
            if (my < deg) {
                const int s = (my < dstg) ? row[my] : ell[(size_t)n * PAD + my];
                const unsigned int v = *(const unsigned int*)(hb_g + (size_t)s * 64 + l32 * 2);
                acc0 += u2lo(v); acc1 += u2hi(v);
            }
        }

        // cross-half combine; redistribute to lane = channel
        acc0 += __shfl_xor(acc0, 32, 64);
        acc1 += __shfl_xor(acc1, 32, 64);
        const int p = lane >> 1;
        const float e0 = __shfl(acc0, p, 64);
        const float e1 = __shfl(acc1, p, 64);
        const float acc = (lane & 1) ? e1 : e0;

        float h  = fmaxf(fmaf(xx0, w0, fmaf(xx1, w1, fmaf(xx2, w2, bb1))), 0.f);
        float h2 = fmaxf(fmaf(di, acc, bgl), 0.f);

        float sum = h + h2;
#pragma unroll
        for (int o = 32; o > 0; o >>= 1) sum += __shfl_xor(sum, o, 64);
        const float mu = sum * (1.0f / 128.0f);

        const float dA = h  - mu;
        const float dB = h2 - mu;
        float vs = dA * dA + dB * dB;
#pragma unroll
        for (int o = 32; o > 0; o >>= 1) vs += __shfl_xor(vs, o, 64);
        const float rr = rsqrtf(vs * (1.0f / 128.0f) + EPS_);

        out[(size_t)n * 128 + lane]      = dA * rr * g0 + be0;
        out[(size_t)n * 128 + 64 + lane] = dB * rr * g1 + be1;
    }
}

// ---------------------------------------------------------------------------
extern "C" void kernel_launch(void* const* d_in, const int* in_sizes, int n_in,
                              void* d_out, int out_size, void* d_ws, size_t ws_size,
                              hipStream_t stream)
{
    const float* x     = (const float*)d_in[0];
    const int*   edge  = (const int*)  d_in[1];   // [2, E]: row0 = src, row1 = dst
    const float* W1    = (const float*)d_in[2];
    const float* b1    = (const float*)d_in[3];
    const float* Wg    = (const float*)d_in[4];
    const float* bg    = (const float*)d_in[5];
    const float* gamma = (const float*)d_in[6];
    const float* beta  = (const float*)d_in[7];
    float*       out   = (float*)d_out;

    // Workspace (~38.8 MB): hb_g | ell | cnt  (16B-aligned)
    char*  ws  = (char*)d_ws;
    size_t p   = 0;
    unsigned short* hb_g = (unsigned short*)(ws + p); p += (size_t)N_NODES * 64 * sizeof(unsigned short);
    int*            ell  = (int*)           (ws + p); p += (size_t)N_NODES * PAD * sizeof(int);
    int*            cnt  = (int*)           (ws + p);

    const int* src = edge;
    const int* dst = edge + N_EDGES;

    hipMemsetAsync(cnt, 0, (size_t)N_NODES * sizeof(int), stream);

    fused_edge_lin_kernel<<<NB_EDGE, 256, 0, stream>>>(src, dst, x, W1, b1, Wg,
                                                       cnt, ell, hb_g);
    scale_kernel<<<(N_NODES * 32 + 255) / 256, 256, 0, stream>>>(cnt, (unsigned int*)hb_g);
    gather_final_kernel<<<NB_GATHER, 128, 0, stream>>>(hb_g, cnt, ell,
                                                       x, W1, b1,
                                                       bg, gamma, beta, out);
}